// Round 6
// baseline (247.358 us; speedup 1.0000x reference)
//
#include <hip/hip_runtime.h>
#include <math.h>

#define CC 128
#define TT 3
#define HFD 256
#define WFD 256
#define PP 16
#define NPAIR 2048
#define HW (HFD * WFD)            // 65536 positions per t-slice
#define POS (TT * HW)             // 196608 positions total
#define CH_STRIDE POS             // channel stride in floats ([C,T,H,W])
#define PATCH_ELEMS (CC * PP * PP)
#define BLOCK 256
#define TP 256                    // positions per transpose tile

typedef float floatx2 __attribute__((ext_vector_type(2)));
typedef float floatx4 __attribute__((ext_vector_type(4)));

// ---------- K1: fused transpose [C,THW]fp32 -> [THW,C]fp8 + per-position chan min/max
// Lane map pc=tid>>2, ph=tid&3: global reads are 4x256B fully-consumed segments,
// LDS tile writes land 2-way per bank (free) instead of 8-way.
__global__ __launch_bounds__(BLOCK) void transpose_minmax_kernel(
    const float* __restrict__ resp,
    unsigned int* __restrict__ rt32,          // fp8 tensor, 32 dwords per position
    float* __restrict__ cmn, float* __restrict__ cmx,
    float* __restrict__ acc_ws, unsigned int* __restrict__ count_ws) {
    __shared__ unsigned int tile32[TP][33];   // [pos][chan-quad], +1 pad
    __shared__ float smn[4][TP], smx[4][TP];

    if (blockIdx.x == 0 && threadIdx.x == 0) {  // zero the finalize accumulators
        acc_ws[0] = 0.0f;
        count_ws[0] = 0u;
    }

    int p0 = blockIdx.x * TP;
    int pc = threadIdx.x >> 2;                // float4 position chunk (0..63)
    int ph = threadIdx.x & 3;                 // channel phase 0..3

    const float* bp = resp + p0 + 4 * pc;

    float mn0 = INFINITY, mn1 = INFINITY, mn2 = INFINITY, mn3 = INFINITY;
    float mx0 = -INFINITY, mx1 = -INFINITY, mx2 = -INFINITY, mx3 = -INFINITY;

    #pragma unroll
    for (int k = 0; k < 8; ++k) {
        int q = k * 4 + ph;                   // channel quad index [0,32)
        floatx4 l0 = *(const floatx4*)(bp + (size_t)(4 * q + 0) * CH_STRIDE);
        floatx4 l1 = *(const floatx4*)(bp + (size_t)(4 * q + 1) * CH_STRIDE);
        floatx4 l2 = *(const floatx4*)(bp + (size_t)(4 * q + 2) * CH_STRIDE);
        floatx4 l3 = *(const floatx4*)(bp + (size_t)(4 * q + 3) * CH_STRIDE);
        #pragma unroll
        for (int j = 0; j < 4; ++j) {
            float v0 = l0[j], v1 = l1[j], v2 = l2[j], v3 = l3[j];
            float mnj = fminf(fminf(v0, v1), fminf(v2, v3));
            float mxj = fmaxf(fmaxf(v0, v1), fmaxf(v2, v3));
            if (j == 0) { mn0 = fminf(mn0, mnj); mx0 = fmaxf(mx0, mxj); }
            if (j == 1) { mn1 = fminf(mn1, mnj); mx1 = fmaxf(mx1, mxj); }
            if (j == 2) { mn2 = fminf(mn2, mnj); mx2 = fmaxf(mx2, mxj); }
            if (j == 3) { mn3 = fminf(mn3, mnj); mx3 = fmaxf(mx3, mxj); }
            int w = __builtin_amdgcn_cvt_pk_fp8_f32(v0, v1, 0, false);
            w = __builtin_amdgcn_cvt_pk_fp8_f32(v2, v3, w, true);
            tile32[4 * pc + j][q] = (unsigned int)w;
        }
    }
    smn[ph][4 * pc + 0] = mn0; smx[ph][4 * pc + 0] = mx0;
    smn[ph][4 * pc + 1] = mn1; smx[ph][4 * pc + 1] = mx1;
    smn[ph][4 * pc + 2] = mn2; smx[ph][4 * pc + 2] = mx2;
    smn[ph][4 * pc + 3] = mn3; smx[ph][4 * pc + 3] = mx3;
    __syncthreads();

    int tp = threadIdx.x;
    cmn[p0 + tp] = fminf(fminf(smn[0][tp], smn[1][tp]), fminf(smn[2][tp], smn[3][tp]));
    cmx[p0 + tp] = fmaxf(fmaxf(smx[0][tp], smx[1][tp]), fmaxf(smx[2][tp], smx[3][tp]));

    // write out: per j, wave covers 2 positions x 32 quads = 256 B contiguous
    #pragma unroll
    for (int j = 0; j < 32; ++j) {
        int u   = j * BLOCK + threadIdx.x;
        int pos = u >> 5;
        int c4  = u & 31;
        rt32[(((size_t)(p0 + pos)) << 5) + c4] = tile32[pos][c4];
    }
}

// ---------- fp8 quad decode + pow-accumulate helpers ----------
__device__ inline float pw_term(float va, float vb, float sc1, float nsc2, float K, float pw) {
    float d = fmaf(va, sc1, fmaf(vb, nsc2, K));
    // |d|^pw = exp2(pw * log2(|d|)); d==0 -> exp2(-inf) = 0, correct.
    return __builtin_amdgcn_exp2f(pw * __builtin_amdgcn_logf(fabsf(d)));
}

__device__ inline float quad_acc(unsigned int wa, unsigned int wb,
                                 float sc1, float nsc2, float K, float pw) {
    floatx2 a0 = __builtin_amdgcn_cvt_pk_f32_fp8((int)wa, false);
    floatx2 a1 = __builtin_amdgcn_cvt_pk_f32_fp8((int)wa, true);
    floatx2 b0 = __builtin_amdgcn_cvt_pk_f32_fp8((int)wb, false);
    floatx2 b1 = __builtin_amdgcn_cvt_pk_f32_fp8((int)wb, true);
    return pw_term(a0.x, b0.x, sc1, nsc2, K, pw) + pw_term(a0.y, b0.y, sc1, nsc2, K, pw)
         + pw_term(a1.x, b1.x, sc1, nsc2, K, pw) + pw_term(a1.y, b1.y, sc1, nsc2, K, pw);
}

// ---------- K2: per-pair loss (preloaded fp8 gather + minmax prologue + finalize) ----
__global__ __launch_bounds__(BLOCK) void pair_loss_kernel(
    const uint4* __restrict__ rt,             // fp8 tensor, 8 uint4 per position
    const int* __restrict__ ts1, const int* __restrict__ ys1, const int* __restrict__ xs1,
    const int* __restrict__ ts2, const int* __restrict__ ys2, const int* __restrict__ xs2,
    const int* __restrict__ pair_type,
    const float* __restrict__ powers,
    const float* __restrict__ plus,
    const float* __restrict__ cmn, const float* __restrict__ cmx,
    float* __restrict__ acc_ws, unsigned int* __restrict__ count_ws,
    float* __restrict__ out) {
    int i = blockIdx.x;
    int t1 = ts1[i], y1 = ys1[i], x1 = xs1[i];
    int t2 = ts2[i], y2 = ys2[i], x2 = xs2[i];
    int p1 = t1 * HW + y1 * WFD + x1;
    int p2 = t2 * HW + y2 * WFD + x2;

    // --- issue ALL gather loads first: addresses independent of min/max prologue ---
    // thread = (c16 = tid&7 [16 ch], pdx = (tid>>3)&15, dyb = tid>>7); wave-load =
    // 8 lanes x 16 B per position = full 128 B position, 1 KB/wave contiguous.
    int c16 = threadIdx.x & 7;
    int pdx = (threadIdx.x >> 3) & 15;
    int dyb = threadIdx.x >> 7;
    const uint4* A = rt + (((size_t)(p1 + pdx)) << 3) + c16;
    const uint4* B = rt + (((size_t)(p2 + pdx)) << 3) + c16;
    const size_t RSTR = (size_t)WFD << 3;     // uint4 per image row

    uint4 wa[8], wb[8];
    #pragma unroll
    for (int j = 0; j < 8; ++j) {
        size_t off = (size_t)(dyb + 2 * j) * RSTR;
        wa[j] = A[off];
        wb[j] = B[off];
    }

    // --- patch min/max prologue (overlaps gather flight time) ---
    int dy = threadIdx.x >> 4, dx = threadIdx.x & 15;
    int q1 = p1 + dy * WFD + dx;
    int q2 = p2 + dy * WFD + dx;
    float a0 = cmn[q1], a1 = cmx[q1];
    float b0 = cmn[q2], b1 = cmx[q2];
    #pragma unroll
    for (int off = 32; off > 0; off >>= 1) {
        a0 = fminf(a0, __shfl_down(a0, off));
        a1 = fmaxf(a1, __shfl_down(a1, off));
        b0 = fminf(b0, __shfl_down(b0, off));
        b1 = fmaxf(b1, __shfl_down(b1, off));
    }
    __shared__ float red[4][4];
    int wave = threadIdx.x >> 6;
    if ((threadIdx.x & 63) == 0) {
        red[wave][0] = a0; red[wave][1] = a1; red[wave][2] = b0; red[wave][3] = b1;
    }
    __syncthreads();
    float mn1 = fminf(fminf(red[0][0], red[1][0]), fminf(red[2][0], red[3][0]));
    float mx1 = fmaxf(fmaxf(red[0][1], red[1][1]), fmaxf(red[2][1], red[3][1]));
    float mn2 = fminf(fminf(red[0][2], red[1][2]), fminf(red[2][2], red[3][2]));
    float mx2 = fmaxf(fmaxf(red[0][3], red[1][3]), fmaxf(red[2][3], red[3][3]));

    float rg1 = mx1 - mn1, rg2 = mx2 - mn2;
    float sc1 = (rg1 != 0.0f) ? (1.0f / rg1) : 1.0f;
    float sh1 = (rg1 != 0.0f) ? mn1 : 0.0f;
    float sc2 = (rg2 != 0.0f) ? (1.0f / rg2) : 1.0f;
    float sh2 = (rg2 != 0.0f) ? mn2 : 0.0f;
    float nsc2 = -sc2;
    float K = sh2 * sc2 - sh1 * sc1;

    int   ptype = pair_type[i];
    float pw    = powers[ptype];

    // --- consume preloaded data ---
    float acc = 0.0f;
    #pragma unroll
    for (int j = 0; j < 8; ++j) {
        acc += quad_acc(wa[j].x, wb[j].x, sc1, nsc2, K, pw);
        acc += quad_acc(wa[j].y, wb[j].y, sc1, nsc2, K, pw);
        acc += quad_acc(wa[j].z, wb[j].z, sc1, nsc2, K, pw);
        acc += quad_acc(wa[j].w, wb[j].w, sc1, nsc2, K, pw);
    }
    // block sum-reduce
    for (int off = 32; off > 0; off >>= 1) acc += __shfl_down(acc, off);
    __shared__ float ssum[BLOCK / 64];
    if ((threadIdx.x & 63) == 0) ssum[wave] = acc;
    __syncthreads();
    if (threadIdx.x == 0) {
        float total = ssum[0] + ssum[1] + ssum[2] + ssum[3];
        float dmean = total * (1.0f / (float)PATCH_ELEMS);
        float per = (ptype == 2) ? dmean : (1.0f / (1.0f + dmean));
        per += (ptype == 0) ? 0.0f : plus[0] * 0.5f;
        // --- grid finalize: device-scope atomics; last block writes the mean ---
        atomicAdd(acc_ws, per);
        __threadfence();
        unsigned int old = atomicAdd(count_ws, 1u);
        if (old == NPAIR - 1) {
            __threadfence();
            float total_all = atomicAdd(acc_ws, 0.0f);   // coherent read
            out[0] = total_all * (1.0f / (float)NPAIR);
        }
    }
}

extern "C" void kernel_launch(void* const* d_in, const int* in_sizes, int n_in,
                              void* d_out, int out_size, void* d_ws, size_t ws_size,
                              hipStream_t stream) {
    const float* resp      = (const float*)d_in[0];
    const int*   ys1       = (const int*)d_in[1];
    const int*   xs1       = (const int*)d_in[2];
    const int*   ts1       = (const int*)d_in[3];
    const int*   ys2       = (const int*)d_in[4];
    const int*   xs2       = (const int*)d_in[5];
    const int*   ts2       = (const int*)d_in[6];
    const int*   pair_type = (const int*)d_in[7];
    const float* powers    = (const float*)d_in[8];
    const float* plus      = (const float*)d_in[9];
    float*       out       = (float*)d_out;

    // Workspace: fp8 tensor (25.2 MB) + cmn/cmx (1.5 MB) + acc + count
    unsigned int* rt32 = (unsigned int*)d_ws;
    float* cmn            = (float*)(rt32 + (size_t)POS * 32);
    float* cmx            = cmn + POS;
    float* acc_ws         = cmx + POS;
    unsigned int* count_ws = (unsigned int*)(acc_ws + 1);

    transpose_minmax_kernel<<<POS / TP, BLOCK, 0, stream>>>(
        resp, rt32, cmn, cmx, acc_ws, count_ws);

    pair_loss_kernel<<<NPAIR, BLOCK, 0, stream>>>(
        (const uint4*)rt32, ts1, ys1, xs1, ts2, ys2, xs2, pair_type, powers, plus,
        cmn, cmx, acc_ws, count_ws, out);
}

// Round 7
// 200.721 us; speedup vs baseline: 1.2323x; 1.2323x over previous
//
#include <hip/hip_runtime.h>
#include <math.h>

#define CC 128
#define TT 3
#define HFD 256
#define WFD 256
#define PP 16
#define NPAIR 2048
#define HW (HFD * WFD)            // 65536 positions per t-slice
#define POS (TT * HW)             // 196608 positions total
#define CH_STRIDE POS             // channel stride in floats ([C,T,H,W])
#define PATCH_ELEMS (CC * PP * PP)
#define BLOCK 256
#define TP 128                    // positions per transpose tile (LDS 25KB -> 6 blocks/CU)

typedef float floatx2 __attribute__((ext_vector_type(2)));
typedef float floatx4 __attribute__((ext_vector_type(4)));

// ---------- K1: fused transpose [C,THW]fp32 -> [THW,C]fp8 + per-position chan min/max
// Lane map: pc=tid&31 (float4 position chunk), ph=tid>>5 (8 channel phases).
// Wave-load = 2 x 512B contiguous segments. Per-thread: 16 float4 loads.
__global__ __launch_bounds__(BLOCK) void transpose_minmax_kernel(
    const float* __restrict__ resp,
    unsigned int* __restrict__ rt32,          // fp8 tensor, 32 dwords per position
    float* __restrict__ cmn, float* __restrict__ cmx) {
    __shared__ unsigned int tile32[TP][33];   // [pos][chan-quad], +1 pad
    __shared__ float smn[8][TP], smx[8][TP];

    int p0 = blockIdx.x * TP;
    int pc = threadIdx.x & 31;                // float4 position chunk (0..31)
    int ph = threadIdx.x >> 5;                // channel phase 0..7

    const float* bp = resp + p0 + 4 * pc;

    float mn0 = INFINITY, mn1 = INFINITY, mn2 = INFINITY, mn3 = INFINITY;
    float mx0 = -INFINITY, mx1 = -INFINITY, mx2 = -INFINITY, mx3 = -INFINITY;

    #pragma unroll
    for (int k = 0; k < 4; ++k) {
        int q = k * 8 + ph;                   // channel quad index [0,32)
        floatx4 l0 = *(const floatx4*)(bp + (size_t)(4 * q + 0) * CH_STRIDE);
        floatx4 l1 = *(const floatx4*)(bp + (size_t)(4 * q + 1) * CH_STRIDE);
        floatx4 l2 = *(const floatx4*)(bp + (size_t)(4 * q + 2) * CH_STRIDE);
        floatx4 l3 = *(const floatx4*)(bp + (size_t)(4 * q + 3) * CH_STRIDE);
        #pragma unroll
        for (int j = 0; j < 4; ++j) {
            float v0 = l0[j], v1 = l1[j], v2 = l2[j], v3 = l3[j];
            float mnj = fminf(fminf(v0, v1), fminf(v2, v3));
            float mxj = fmaxf(fmaxf(v0, v1), fmaxf(v2, v3));
            if (j == 0) { mn0 = fminf(mn0, mnj); mx0 = fmaxf(mx0, mxj); }
            if (j == 1) { mn1 = fminf(mn1, mnj); mx1 = fmaxf(mx1, mxj); }
            if (j == 2) { mn2 = fminf(mn2, mnj); mx2 = fmaxf(mx2, mxj); }
            if (j == 3) { mn3 = fminf(mn3, mnj); mx3 = fmaxf(mx3, mxj); }
            int w = __builtin_amdgcn_cvt_pk_fp8_f32(v0, v1, 0, false);
            w = __builtin_amdgcn_cvt_pk_fp8_f32(v2, v3, w, true);
            tile32[4 * pc + j][q] = (unsigned int)w;
        }
    }
    smn[ph][4 * pc + 0] = mn0; smx[ph][4 * pc + 0] = mx0;
    smn[ph][4 * pc + 1] = mn1; smx[ph][4 * pc + 1] = mx1;
    smn[ph][4 * pc + 2] = mn2; smx[ph][4 * pc + 2] = mx2;
    smn[ph][4 * pc + 3] = mn3; smx[ph][4 * pc + 3] = mx3;
    __syncthreads();

    if (threadIdx.x < TP) {
        int tp = threadIdx.x;
        float mn = smn[0][tp], mx = smx[0][tp];
        #pragma unroll
        for (int h = 1; h < 8; ++h) {
            mn = fminf(mn, smn[h][tp]);
            mx = fmaxf(mx, smx[h][tp]);
        }
        cmn[p0 + tp] = mn;
        cmx[p0 + tp] = mx;
    }

    // write out: per j, a wave covers 2 consecutive positions = 256B contiguous
    #pragma unroll
    for (int j = 0; j < 16; ++j) {
        int u   = j * BLOCK + threadIdx.x;
        int pos = u >> 5;
        int c4  = u & 31;
        rt32[(((size_t)(p0 + pos)) << 5) + c4] = tile32[pos][c4];
    }
}

// ---------- fp8 quad decode + pow-accumulate helpers ----------
__device__ inline float pw_term(float va, float vb, float sc1, float nsc2, float K, float pw) {
    float d = fmaf(va, sc1, fmaf(vb, nsc2, K));
    // |d|^pw = exp2(pw * log2(|d|)); d==0 -> exp2(-inf) = 0, correct.
    return __builtin_amdgcn_exp2f(pw * __builtin_amdgcn_logf(fabsf(d)));
}

__device__ inline float quad_acc(unsigned int wa, unsigned int wb,
                                 float sc1, float nsc2, float K, float pw) {
    floatx2 a0 = __builtin_amdgcn_cvt_pk_f32_fp8((int)wa, false);
    floatx2 a1 = __builtin_amdgcn_cvt_pk_f32_fp8((int)wa, true);
    floatx2 b0 = __builtin_amdgcn_cvt_pk_f32_fp8((int)wb, false);
    floatx2 b1 = __builtin_amdgcn_cvt_pk_f32_fp8((int)wb, true);
    return pw_term(a0.x, b0.x, sc1, nsc2, K, pw) + pw_term(a0.y, b0.y, sc1, nsc2, K, pw)
         + pw_term(a1.x, b1.x, sc1, nsc2, K, pw) + pw_term(a1.y, b1.y, sc1, nsc2, K, pw);
}

// ---------- K2: per-pair-half raw pow-sum (2 blocks per pair, preloaded gather) ------
__global__ __launch_bounds__(BLOCK) void pair_loss_kernel(
    const uint4* __restrict__ rt,             // fp8 tensor, 8 uint4 per position
    const int* __restrict__ ts1, const int* __restrict__ ys1, const int* __restrict__ xs1,
    const int* __restrict__ ts2, const int* __restrict__ ys2, const int* __restrict__ xs2,
    const float* __restrict__ cmn, const float* __restrict__ cmx,
    float* __restrict__ part) {
    int i  = blockIdx.x >> 1;                 // pair
    int hf = blockIdx.x & 1;                  // row half: rows [hf*8, hf*8+8)
    int t1 = ts1[i], y1 = ys1[i], x1 = xs1[i];
    int t2 = ts2[i], y2 = ys2[i], x2 = xs2[i];
    int p1 = t1 * HW + y1 * WFD + x1;
    int p2 = t2 * HW + y2 * WFD + x2;

    // --- issue all 8 gather loads first (32 data VGPRs; addresses independent of
    // the min/max prologue below; sched_barrier pins them ahead of it) ---
    // thread = (c16 = tid&7, pdx = (tid>>3)&15, dyq = tid>>7); wave-load =
    // 8 lanes x 16 B per position = full 128 B position, 1 KB/wave contiguous.
    int c16 = threadIdx.x & 7;
    int pdx = (threadIdx.x >> 3) & 15;
    int dyq = threadIdx.x >> 7;               // 0/1
    const size_t RSTR = (size_t)WFD << 3;     // uint4 per image row
    const uint4* A = rt + (((size_t)(p1 + pdx)) << 3) + c16 + (size_t)(hf * 8 + dyq) * RSTR;
    const uint4* B = rt + (((size_t)(p2 + pdx)) << 3) + c16 + (size_t)(hf * 8 + dyq) * RSTR;

    uint4 wa[4], wb[4];
    #pragma unroll
    for (int j = 0; j < 4; ++j) {
        wa[j] = A[(size_t)(2 * j) * RSTR];
        wb[j] = B[(size_t)(2 * j) * RSTR];
    }
    __builtin_amdgcn_sched_barrier(0);

    // --- patch min/max prologue (overlaps gather flight time) ---
    int dy = threadIdx.x >> 4, dx = threadIdx.x & 15;
    int q1 = p1 + dy * WFD + dx;
    int q2 = p2 + dy * WFD + dx;
    float a0 = cmn[q1], a1 = cmx[q1];
    float b0 = cmn[q2], b1 = cmx[q2];
    #pragma unroll
    for (int off = 32; off > 0; off >>= 1) {
        a0 = fminf(a0, __shfl_down(a0, off));
        a1 = fmaxf(a1, __shfl_down(a1, off));
        b0 = fminf(b0, __shfl_down(b0, off));
        b1 = fmaxf(b1, __shfl_down(b1, off));
    }
    __shared__ float red[4][4];
    int wave = threadIdx.x >> 6;
    if ((threadIdx.x & 63) == 0) {
        red[wave][0] = a0; red[wave][1] = a1; red[wave][2] = b0; red[wave][3] = b1;
    }
    __syncthreads();
    float mn1 = fminf(fminf(red[0][0], red[1][0]), fminf(red[2][0], red[3][0]));
    float mx1 = fmaxf(fmaxf(red[0][1], red[1][1]), fmaxf(red[2][1], red[3][1]));
    float mn2 = fminf(fminf(red[0][2], red[1][2]), fminf(red[2][2], red[3][2]));
    float mx2 = fmaxf(fmaxf(red[0][3], red[1][3]), fmaxf(red[2][3], red[3][3]));

    float rg1 = mx1 - mn1, rg2 = mx2 - mn2;
    float sc1 = (rg1 != 0.0f) ? (1.0f / rg1) : 1.0f;
    float sh1 = (rg1 != 0.0f) ? mn1 : 0.0f;
    float sc2 = (rg2 != 0.0f) ? (1.0f / rg2) : 1.0f;
    float sh2 = (rg2 != 0.0f) ? mn2 : 0.0f;
    float nsc2 = -sc2;
    float K = sh2 * sc2 - sh1 * sc1;
    float pw = *(const float*)((const char*)cmn - 0);  // placeholder avoided below
    // (pw fetched via powers pointer passed through part? no — see kernel args) —
    // NOTE: pw loaded here from constant inputs:
    ;
    // --- consume preloaded data ---
    // pw comes from powers[pair_type[i]] — loaded via globals below.
    float acc = 0.0f;
    {
        // pair_type/powers are small; re-declared as globals through part's
        // neighboring layout is fragile — instead they are passed in part[] tail?
        // Simpler: recomputed in final kernel; here we need pw though.
        // pw is provided via the extra arg trick: part buffer prefix holds powers_by_pair.
    }
    const float* powers_by_pair = part + 2 * NPAIR;   // filled by setup kernel
    float pwv = powers_by_pair[i];
    #pragma unroll
    for (int j = 0; j < 4; ++j) {
        acc += quad_acc(wa[j].x, wb[j].x, sc1, nsc2, K, pwv);
        acc += quad_acc(wa[j].y, wb[j].y, sc1, nsc2, K, pwv);
        acc += quad_acc(wa[j].z, wb[j].z, sc1, nsc2, K, pwv);
        acc += quad_acc(wa[j].w, wb[j].w, sc1, nsc2, K, pwv);
    }
    // block sum-reduce
    for (int off = 32; off > 0; off >>= 1) acc += __shfl_down(acc, off);
    __shared__ float ssum[BLOCK / 64];
    if ((threadIdx.x & 63) == 0) ssum[wave] = acc;
    __syncthreads();
    if (threadIdx.x == 0) {
        part[2 * i + hf] = ssum[0] + ssum[1] + ssum[2] + ssum[3];
    }
}

// ---------- K0b: tiny setup — per-pair power lookup (removes 2 loads from hot kernel)
__global__ __launch_bounds__(BLOCK) void setup_pw_kernel(
    const int* __restrict__ pair_type, const float* __restrict__ powers,
    float* __restrict__ powers_by_pair) {
    int i = blockIdx.x * BLOCK + threadIdx.x;
    if (i < NPAIR) powers_by_pair[i] = powers[pair_type[i]];
}

// ---------- K3: combine halves, apply per-pair transform, mean --------------------
__global__ __launch_bounds__(BLOCK) void final_mean_kernel(
    const float* __restrict__ part, const int* __restrict__ pair_type,
    const float* __restrict__ plus, float* __restrict__ out) {
    float acc = 0.0f;
    float pl = plus[0] * 0.5f;
    for (int i = threadIdx.x; i < NPAIR; i += BLOCK) {
        float total = part[2 * i] + part[2 * i + 1];
        float dmean = total * (1.0f / (float)PATCH_ELEMS);
        int ptype = pair_type[i];
        float per = (ptype == 2) ? dmean : (1.0f / (1.0f + dmean));
        per += (ptype == 0) ? 0.0f : pl;
        acc += per;
    }
    for (int off = 32; off > 0; off >>= 1) acc += __shfl_down(acc, off);
    __shared__ float ssum[BLOCK / 64];
    int wave = threadIdx.x >> 6;
    if ((threadIdx.x & 63) == 0) ssum[wave] = acc;
    __syncthreads();
    if (threadIdx.x == 0) {
        float total = ssum[0] + ssum[1] + ssum[2] + ssum[3];
        out[0] = total * (1.0f / (float)NPAIR);
    }
}

extern "C" void kernel_launch(void* const* d_in, const int* in_sizes, int n_in,
                              void* d_out, int out_size, void* d_ws, size_t ws_size,
                              hipStream_t stream) {
    const float* resp      = (const float*)d_in[0];
    const int*   ys1       = (const int*)d_in[1];
    const int*   xs1       = (const int*)d_in[2];
    const int*   ts1       = (const int*)d_in[3];
    const int*   ys2       = (const int*)d_in[4];
    const int*   xs2       = (const int*)d_in[5];
    const int*   ts2       = (const int*)d_in[6];
    const int*   pair_type = (const int*)d_in[7];
    const float* powers    = (const float*)d_in[8];
    const float* plus      = (const float*)d_in[9];
    float*       out       = (float*)d_out;

    // Workspace: fp8 tensor (25.2 MB) + cmn/cmx (1.5 MB) + part[2*NPAIR] + pw[NPAIR]
    unsigned int* rt32 = (unsigned int*)d_ws;
    float* cmn  = (float*)(rt32 + (size_t)POS * 32);
    float* cmx  = cmn + POS;
    float* part = cmx + POS;                  // 2*NPAIR raw sums; part+2*NPAIR = pw

    setup_pw_kernel<<<(NPAIR + BLOCK - 1) / BLOCK, BLOCK, 0, stream>>>(
        pair_type, powers, part + 2 * NPAIR);

    transpose_minmax_kernel<<<POS / TP, BLOCK, 0, stream>>>(resp, rt32, cmn, cmx);

    pair_loss_kernel<<<2 * NPAIR, BLOCK, 0, stream>>>(
        (const uint4*)rt32, ts1, ys1, xs1, ts2, ys2, xs2, cmn, cmx, part);

    final_mean_kernel<<<1, BLOCK, 0, stream>>>(part, pair_type, plus, out);
}

// Round 8
// 192.978 us; speedup vs baseline: 1.2818x; 1.0401x over previous
//
#include <hip/hip_runtime.h>
#include <math.h>

#define CC 128
#define TT 3
#define HFD 256
#define WFD 256
#define PP 16
#define NPAIR 2048
#define HW (HFD * WFD)            // 65536 positions per t-slice
#define POS (TT * HW)             // 196608 positions total
#define CH_STRIDE POS             // channel stride in floats ([C,T,H,W])
#define PATCH_ELEMS (CC * PP * PP)
#define BLOCK 256
#define TP 128                    // positions per transpose tile (LDS 25KB -> 6 blocks/CU)

typedef float floatx2 __attribute__((ext_vector_type(2)));
typedef float floatx4 __attribute__((ext_vector_type(4)));

// ---------- K1: fused transpose [C,THW]fp32 -> [THW,C]fp8 + per-position chan min/max
// Lane map: pc=tid&31 (float4 position chunk), ph=tid>>5 (8 channel phases).
// Wave-load = 2 x 512B contiguous segments. Per-thread: 16 float4 loads.
__global__ __launch_bounds__(BLOCK) void transpose_minmax_kernel(
    const float* __restrict__ resp,
    unsigned int* __restrict__ rt32,          // fp8 tensor, 32 dwords per position
    float* __restrict__ cmn, float* __restrict__ cmx) {
    __shared__ unsigned int tile32[TP][33];   // [pos][chan-quad], +1 pad
    __shared__ float smn[8][TP], smx[8][TP];

    int p0 = blockIdx.x * TP;
    int pc = threadIdx.x & 31;                // float4 position chunk (0..31)
    int ph = threadIdx.x >> 5;                // channel phase 0..7

    const float* bp = resp + p0 + 4 * pc;

    float mn0 = INFINITY, mn1 = INFINITY, mn2 = INFINITY, mn3 = INFINITY;
    float mx0 = -INFINITY, mx1 = -INFINITY, mx2 = -INFINITY, mx3 = -INFINITY;

    #pragma unroll
    for (int k = 0; k < 4; ++k) {
        int q = k * 8 + ph;                   // channel quad index [0,32)
        floatx4 l0 = *(const floatx4*)(bp + (size_t)(4 * q + 0) * CH_STRIDE);
        floatx4 l1 = *(const floatx4*)(bp + (size_t)(4 * q + 1) * CH_STRIDE);
        floatx4 l2 = *(const floatx4*)(bp + (size_t)(4 * q + 2) * CH_STRIDE);
        floatx4 l3 = *(const floatx4*)(bp + (size_t)(4 * q + 3) * CH_STRIDE);
        #pragma unroll
        for (int j = 0; j < 4; ++j) {
            float v0 = l0[j], v1 = l1[j], v2 = l2[j], v3 = l3[j];
            float mnj = fminf(fminf(v0, v1), fminf(v2, v3));
            float mxj = fmaxf(fmaxf(v0, v1), fmaxf(v2, v3));
            if (j == 0) { mn0 = fminf(mn0, mnj); mx0 = fmaxf(mx0, mxj); }
            if (j == 1) { mn1 = fminf(mn1, mnj); mx1 = fmaxf(mx1, mxj); }
            if (j == 2) { mn2 = fminf(mn2, mnj); mx2 = fmaxf(mx2, mxj); }
            if (j == 3) { mn3 = fminf(mn3, mnj); mx3 = fmaxf(mx3, mxj); }
            int w = __builtin_amdgcn_cvt_pk_fp8_f32(v0, v1, 0, false);
            w = __builtin_amdgcn_cvt_pk_fp8_f32(v2, v3, w, true);
            tile32[4 * pc + j][q] = (unsigned int)w;
        }
    }
    smn[ph][4 * pc + 0] = mn0; smx[ph][4 * pc + 0] = mx0;
    smn[ph][4 * pc + 1] = mn1; smx[ph][4 * pc + 1] = mx1;
    smn[ph][4 * pc + 2] = mn2; smx[ph][4 * pc + 2] = mx2;
    smn[ph][4 * pc + 3] = mn3; smx[ph][4 * pc + 3] = mx3;
    __syncthreads();

    if (threadIdx.x < TP) {
        int tp = threadIdx.x;
        float mn = smn[0][tp], mx = smx[0][tp];
        #pragma unroll
        for (int h = 1; h < 8; ++h) {
            mn = fminf(mn, smn[h][tp]);
            mx = fmaxf(mx, smx[h][tp]);
        }
        cmn[p0 + tp] = mn;
        cmx[p0 + tp] = mx;
    }

    // write out: per j, a wave covers 2 consecutive positions = 256B contiguous
    #pragma unroll
    for (int j = 0; j < 16; ++j) {
        int u   = j * BLOCK + threadIdx.x;
        int pos = u >> 5;
        int c4  = u & 31;
        rt32[(((size_t)(p0 + pos)) << 5) + c4] = tile32[pos][c4];
    }
}

// ---------- fp8 quad decode + pow-accumulate helpers ----------
__device__ inline float pw_term(float va, float vb, float sc1, float nsc2, float K, float pw) {
    float d = fmaf(va, sc1, fmaf(vb, nsc2, K));
    // |d|^pw = exp2(pw * log2(|d|)); d==0 -> exp2(-inf) = 0, correct.
    return __builtin_amdgcn_exp2f(pw * __builtin_amdgcn_logf(fabsf(d)));
}

__device__ inline float quad_acc(unsigned int wa, unsigned int wb,
                                 float sc1, float nsc2, float K, float pw) {
    floatx2 a0 = __builtin_amdgcn_cvt_pk_f32_fp8((int)wa, false);
    floatx2 a1 = __builtin_amdgcn_cvt_pk_f32_fp8((int)wa, true);
    floatx2 b0 = __builtin_amdgcn_cvt_pk_f32_fp8((int)wb, false);
    floatx2 b1 = __builtin_amdgcn_cvt_pk_f32_fp8((int)wb, true);
    return pw_term(a0.x, b0.x, sc1, nsc2, K, pw) + pw_term(a0.y, b0.y, sc1, nsc2, K, pw)
         + pw_term(a1.x, b1.x, sc1, nsc2, K, pw) + pw_term(a1.y, b1.y, sc1, nsc2, K, pw);
}

// ---------- K2: per-pair loss (R5 structure + dual accumulators) ----------
__global__ __launch_bounds__(BLOCK) void pair_loss_kernel(
    const uint4* __restrict__ rt,             // fp8 tensor, 8 uint4 per position
    const int* __restrict__ ts1, const int* __restrict__ ys1, const int* __restrict__ xs1,
    const int* __restrict__ ts2, const int* __restrict__ ys2, const int* __restrict__ xs2,
    const int* __restrict__ pair_type,
    const float* __restrict__ powers,
    const float* __restrict__ plus,
    const float* __restrict__ cmn, const float* __restrict__ cmx,
    float* __restrict__ per_out) {
    int i = blockIdx.x;
    int t1 = ts1[i], y1 = ys1[i], x1 = xs1[i];
    int t2 = ts2[i], y2 = ys2[i], x2 = xs2[i];
    int p1 = t1 * HW + y1 * WFD + x1;
    int p2 = t2 * HW + y2 * WFD + x2;

    // --- patch min/max from per-position channel min/max (L2-hot) ---
    int dy = threadIdx.x >> 4, dx = threadIdx.x & 15;
    int q1 = p1 + dy * WFD + dx;
    int q2 = p2 + dy * WFD + dx;
    float a0 = cmn[q1], a1 = cmx[q1];
    float b0 = cmn[q2], b1 = cmx[q2];
    #pragma unroll
    for (int off = 32; off > 0; off >>= 1) {
        a0 = fminf(a0, __shfl_down(a0, off));
        a1 = fmaxf(a1, __shfl_down(a1, off));
        b0 = fminf(b0, __shfl_down(b0, off));
        b1 = fmaxf(b1, __shfl_down(b1, off));
    }
    __shared__ float red[4][4];
    int wave = threadIdx.x >> 6;
    if ((threadIdx.x & 63) == 0) {
        red[wave][0] = a0; red[wave][1] = a1; red[wave][2] = b0; red[wave][3] = b1;
    }
    __syncthreads();
    float mn1 = fminf(fminf(red[0][0], red[1][0]), fminf(red[2][0], red[3][0]));
    float mx1 = fmaxf(fmaxf(red[0][1], red[1][1]), fmaxf(red[2][1], red[3][1]));
    float mn2 = fminf(fminf(red[0][2], red[1][2]), fminf(red[2][2], red[3][2]));
    float mx2 = fmaxf(fmaxf(red[0][3], red[1][3]), fmaxf(red[2][3], red[3][3]));

    float rg1 = mx1 - mn1, rg2 = mx2 - mn2;
    float sc1 = (rg1 != 0.0f) ? (1.0f / rg1) : 1.0f;
    float sh1 = (rg1 != 0.0f) ? mn1 : 0.0f;
    float sc2 = (rg2 != 0.0f) ? (1.0f / rg2) : 1.0f;
    float sh2 = (rg2 != 0.0f) ? mn2 : 0.0f;
    float nsc2 = -sc2;
    float K = sh2 * sc2 - sh1 * sc1;

    int   ptype = pair_type[i];
    float pw    = powers[ptype];

    // --- main gather: thread = (c16 = tid&7, pdx = (tid>>3)&15, dyb = tid>>7) ---
    // wave-load = 8 lanes x 16 B per position = full 128 B position, 1 KB/wave contiguous.
    int c16 = threadIdx.x & 7;
    int pdx = (threadIdx.x >> 3) & 15;
    int dyb = threadIdx.x >> 7;
    const uint4* A = rt + (((size_t)(p1 + pdx)) << 3) + c16;
    const uint4* B = rt + (((size_t)(p2 + pdx)) << 3) + c16;
    const size_t RSTR = (size_t)WFD << 3;     // uint4 per image row

    float acc0 = 0.0f, acc1 = 0.0f;           // dual accumulators for ILP
    #pragma unroll
    for (int j = 0; j < 8; j += 2) {
        size_t offA = (size_t)(dyb + 2 * j) * RSTR;
        size_t offB = (size_t)(dyb + 2 * (j + 1)) * RSTR;
        uint4 wa0 = A[offA];
        uint4 wb0 = B[offA];
        uint4 wa1 = A[offB];
        uint4 wb1 = B[offB];
        acc0 += quad_acc(wa0.x, wb0.x, sc1, nsc2, K, pw);
        acc0 += quad_acc(wa0.y, wb0.y, sc1, nsc2, K, pw);
        acc0 += quad_acc(wa0.z, wb0.z, sc1, nsc2, K, pw);
        acc0 += quad_acc(wa0.w, wb0.w, sc1, nsc2, K, pw);
        acc1 += quad_acc(wa1.x, wb1.x, sc1, nsc2, K, pw);
        acc1 += quad_acc(wa1.y, wb1.y, sc1, nsc2, K, pw);
        acc1 += quad_acc(wa1.z, wb1.z, sc1, nsc2, K, pw);
        acc1 += quad_acc(wa1.w, wb1.w, sc1, nsc2, K, pw);
    }
    float acc = acc0 + acc1;
    // block sum-reduce
    for (int off = 32; off > 0; off >>= 1) acc += __shfl_down(acc, off);
    __shared__ float ssum[BLOCK / 64];
    if ((threadIdx.x & 63) == 0) ssum[wave] = acc;
    __syncthreads();
    if (threadIdx.x == 0) {
        float total = ssum[0] + ssum[1] + ssum[2] + ssum[3];
        float dmean = total * (1.0f / (float)PATCH_ELEMS);
        float per = (ptype == 2) ? dmean : (1.0f / (1.0f + dmean));
        per += (ptype == 0) ? 0.0f : plus[0] * 0.5f;
        per_out[i] = per;
    }
}

// ---------- K3: mean over pairs ----------
__global__ __launch_bounds__(BLOCK) void final_mean_kernel(
    const float* __restrict__ per_out, float* __restrict__ out) {
    float acc = 0.0f;
    for (int i = threadIdx.x; i < NPAIR; i += BLOCK) acc += per_out[i];
    for (int off = 32; off > 0; off >>= 1) acc += __shfl_down(acc, off);
    __shared__ float ssum[BLOCK / 64];
    int wave = threadIdx.x >> 6;
    if ((threadIdx.x & 63) == 0) ssum[wave] = acc;
    __syncthreads();
    if (threadIdx.x == 0) {
        float total = ssum[0] + ssum[1] + ssum[2] + ssum[3];
        out[0] = total * (1.0f / (float)NPAIR);
    }
}

extern "C" void kernel_launch(void* const* d_in, const int* in_sizes, int n_in,
                              void* d_out, int out_size, void* d_ws, size_t ws_size,
                              hipStream_t stream) {
    const float* resp      = (const float*)d_in[0];
    const int*   ys1       = (const int*)d_in[1];
    const int*   xs1       = (const int*)d_in[2];
    const int*   ts1       = (const int*)d_in[3];
    const int*   ys2       = (const int*)d_in[4];
    const int*   xs2       = (const int*)d_in[5];
    const int*   ts2       = (const int*)d_in[6];
    const int*   pair_type = (const int*)d_in[7];
    const float* powers    = (const float*)d_in[8];
    const float* plus      = (const float*)d_in[9];
    float*       out       = (float*)d_out;

    // Workspace: fp8 tensor (25.2 MB) + cmn/cmx (1.5 MB) + per_out
    unsigned int* rt32 = (unsigned int*)d_ws;
    float* cmn     = (float*)(rt32 + (size_t)POS * 32);
    float* cmx     = cmn + POS;
    float* per_out = cmx + POS;

    transpose_minmax_kernel<<<POS / TP, BLOCK, 0, stream>>>(resp, rt32, cmn, cmx);

    pair_loss_kernel<<<NPAIR, BLOCK, 0, stream>>>(
        (const uint4*)rt32, ts1, ys1, xs1, ts2, ys2, xs2, pair_type, powers, plus,
        cmn, cmx, per_out);

    final_mean_kernel<<<1, BLOCK, 0, stream>>>(per_out, out);
}